// Round 14
// baseline (428.352 us; speedup 1.0000x reference)
//
#include <hip/hip_runtime.h>
#include <hip/hip_bf16.h>

#define NN 50000

typedef short short8 __attribute__((ext_vector_type(8)));
typedef float f32x4 __attribute__((ext_vector_type(4)));

__device__ __forceinline__ unsigned short f2bf(float f) {
    unsigned int b = __float_as_uint(f);
    unsigned int r = (b + 0x7FFFu + ((b >> 16) & 1u)) >> 16;   // RNE
    return (unsigned short)r;
}
__device__ __forceinline__ float bf2f(unsigned short u) {
    return __uint_as_float((unsigned int)u << 16);
}

// ---------------- CSR build ----------------

__global__ void hist_rank_kernel(const int* __restrict__ dst, int* counts,
                                 int* __restrict__ rank, int E) {
    int i = blockIdx.x * blockDim.x + threadIdx.x;
    if (i < E) rank[i] = atomicAdd(&counts[dst[i]], 1);
}

__global__ __launch_bounds__(256) void alloc_kernel(const int* __restrict__ counts,
                                                    int* __restrict__ row_beg,
                                                    int* total, int n) {
    int i = blockIdx.x * blockDim.x + threadIdx.x;
    int lane = threadIdx.x & 63;
    int len = (i < n) ? (counts[i] + 1) : 0;
    int p = len;
    #pragma unroll
    for (int off = 1; off < 64; off <<= 1) {
        int t = __shfl_up(p, off);
        if (lane >= off) p += t;
    }
    int tot = __shfl(p, 63);
    int base = 0;
    if (lane == 63) base = atomicAdd(total, tot);
    base = __shfl(base, 63);
    if (i < n) row_beg[i] = base + p - len;
}

__global__ void scatter_kernel(const int* __restrict__ src, const int* __restrict__ dst,
                               const int* __restrict__ rank, const int* __restrict__ row_beg,
                               const int* __restrict__ counts,
                               int* __restrict__ col, int E, int n) {
    int i = blockIdx.x * blockDim.x + threadIdx.x;
    if (i >= E + n) return;
    if (i < E) {
        col[row_beg[dst[i]] + rank[i]] = src[i];
    } else {
        int v = i - E;
        col[row_beg[v] + counts[v]] = v;
    }
}

// ---------------- bf16 conversions (fused: x, W_src|W_dst, W_in) ----------------
__global__ __launch_bounds__(256) void convert_all_kernel(const float* __restrict__ x,
                                                          const float* __restrict__ Ws,
                                                          const float* __restrict__ Wd,
                                                          const float* __restrict__ Win,
                                                          unsigned short* __restrict__ xB,
                                                          unsigned short* __restrict__ WtL,
                                                          unsigned short* __restrict__ WtIn) {
    int blk = blockIdx.x;
    if (blk < 3125) {
        int i = blk * 256 + threadIdx.x;
        float4 v = ((const float4*)x)[i];
        ushort4 o;
        o.x = f2bf(v.x); o.y = f2bf(v.y); o.z = f2bf(v.z); o.w = f2bf(v.w);
        ((ushort4*)xB)[i] = o;
    } else if (blk < 3125 + 384) {
        int e = (blk - 3125) * 256 + threadIdx.x;
        int l = e >> 15;
        int r = e & 32767;
        int colc = r >> 7;
        int k = r & 127;
        float v = (colc < 128) ? Ws[l * 16384 + k * 128 + colc]
                               : Wd[l * 16384 + k * 128 + (colc - 128)];
        WtL[l * 32768 + colc * 128 + k] = f2bf(v);
    } else {
        int e = (blk - 3509) * 256 + threadIdx.x;
        int colc = e >> 6;
        int k = e & 63;
        WtIn[colc * 64 + k] = f2bf(Win[k * 128 + colc]);
    }
}

// ---------------- MFMA GEMMs ----------------
// Both GEMMs process TWO 16-row groups per grid-stride iteration: 32 A-frag
// loads issue before the MFMA block, doubling MFMA work per exposed global
// latency (the single-rg version was latency-serial at ~3% of MFMA peak).
// in_proj: x_bf16[N,64] @ W_in[64,128] + b -> hB (bf16 only; hA eliminated).
__global__ __launch_bounds__(256, 4) void in_proj_mfma(const unsigned short* __restrict__ xB,
                                                       const unsigned short* __restrict__ Wt,
                                                       const float* __restrict__ b,
                                                       unsigned short* __restrict__ hB) {
    int tid = threadIdx.x;
    int w = tid >> 6, l = tid & 63;
    int m = l & 15, q = l >> 4;
    short8 B[2][2];
    #pragma unroll
    for (int ct = 0; ct < 2; ++ct) {
        int col = w * 32 + ct * 16 + m;
        const unsigned short* wp = Wt + col * 64 + q * 8;
        #pragma unroll
        for (int kt = 0; kt < 2; ++kt) B[ct][kt] = *(const short8*)(wp + kt * 32);
    }
    float bias[2];
    #pragma unroll
    for (int ct = 0; ct < 2; ++ct) bias[ct] = b[w * 32 + ct * 16 + m];
    const int NPG = (NN + 31) / 32;   // 1563 (last group single)
    for (int pg = blockIdx.x; pg < NPG; pg += gridDim.x) {
        int row0 = pg * 32;
        bool two = (row0 + 16 < NN);
        const unsigned short* ap0 = xB + (size_t)(row0 + m) * 64 + q * 8;
        short8 A0[2], A1[2];
        #pragma unroll
        for (int kt = 0; kt < 2; ++kt) A0[kt] = *(const short8*)(ap0 + kt * 32);
        if (two) {
            const unsigned short* ap1 = ap0 + 16 * 64;
            #pragma unroll
            for (int kt = 0; kt < 2; ++kt) A1[kt] = *(const short8*)(ap1 + kt * 32);
        }
        f32x4 acc0[2], acc1[2];
        #pragma unroll
        for (int ct = 0; ct < 2; ++ct) {
            acc0[ct] = (f32x4){0.f, 0.f, 0.f, 0.f};
            acc1[ct] = (f32x4){0.f, 0.f, 0.f, 0.f};
        }
        #pragma unroll
        for (int kt = 0; kt < 2; ++kt)
            #pragma unroll
            for (int ct = 0; ct < 2; ++ct)
                acc0[ct] = __builtin_amdgcn_mfma_f32_16x16x32_bf16(A0[kt], B[ct][kt], acc0[ct], 0, 0, 0);
        if (two) {
            #pragma unroll
            for (int kt = 0; kt < 2; ++kt)
                #pragma unroll
                for (int ct = 0; ct < 2; ++ct)
                    acc1[ct] = __builtin_amdgcn_mfma_f32_16x16x32_bf16(A1[kt], B[ct][kt], acc1[ct], 0, 0, 0);
        }
        #pragma unroll
        for (int ct = 0; ct < 2; ++ct) {
            int col = w * 32 + ct * 16 + m;
            #pragma unroll
            for (int i = 0; i < 4; ++i) {
                int row = row0 + q * 4 + i;
                hB[(size_t)row * 128 + col] = f2bf(acc0[ct][i] + bias[ct]);
                if (two) hB[(size_t)(row + 16) * 128 + col] = f2bf(acc1[ct][i] + bias[ct]);
            }
        }
    }
}

// dual: hB[N,128] @ [Ws|Wd][128,256] + bias -> fsB, fdB (bf16).
__global__ __launch_bounds__(256, 3) void dual_gemm_mfma(const unsigned short* __restrict__ hB,
                                                         const unsigned short* __restrict__ Wt,
                                                         const float* __restrict__ bs,
                                                         const float* __restrict__ bd,
                                                         unsigned short* __restrict__ fsB,
                                                         unsigned short* __restrict__ fdB) {
    int tid = threadIdx.x;
    int w = tid >> 6, l = tid & 63;
    int m = l & 15, q = l >> 4;
    short8 B[4][4];
    #pragma unroll
    for (int ct = 0; ct < 4; ++ct) {
        int col = w * 64 + ct * 16 + m;
        const unsigned short* wp = Wt + col * 128 + q * 8;
        #pragma unroll
        for (int kt = 0; kt < 4; ++kt) B[ct][kt] = *(const short8*)(wp + kt * 32);
    }
    const float* bptr = (w < 2) ? bs : bd;
    unsigned short* OUT = (w < 2) ? fsB : fdB;
    int ocb = (w * 64) & 127;
    float bias[4];
    #pragma unroll
    for (int ct = 0; ct < 4; ++ct) bias[ct] = bptr[ocb + ct * 16 + m];
    const int NPG = (NN + 31) / 32;
    for (int pg = blockIdx.x; pg < NPG; pg += gridDim.x) {
        int row0 = pg * 32;
        bool two = (row0 + 16 < NN);
        const unsigned short* ap0 = hB + (size_t)(row0 + m) * 128 + q * 8;
        short8 A0[4], A1[4];
        #pragma unroll
        for (int kt = 0; kt < 4; ++kt) A0[kt] = *(const short8*)(ap0 + kt * 32);
        if (two) {
            const unsigned short* ap1 = ap0 + 16 * 128;
            #pragma unroll
            for (int kt = 0; kt < 4; ++kt) A1[kt] = *(const short8*)(ap1 + kt * 32);
        }
        f32x4 acc0[4], acc1[4];
        #pragma unroll
        for (int ct = 0; ct < 4; ++ct) {
            acc0[ct] = (f32x4){0.f, 0.f, 0.f, 0.f};
            acc1[ct] = (f32x4){0.f, 0.f, 0.f, 0.f};
        }
        #pragma unroll
        for (int kt = 0; kt < 4; ++kt)
            #pragma unroll
            for (int ct = 0; ct < 4; ++ct)
                acc0[ct] = __builtin_amdgcn_mfma_f32_16x16x32_bf16(A0[kt], B[ct][kt], acc0[ct], 0, 0, 0);
        if (two) {
            #pragma unroll
            for (int kt = 0; kt < 4; ++kt)
                #pragma unroll
                for (int ct = 0; ct < 4; ++ct)
                    acc1[ct] = __builtin_amdgcn_mfma_f32_16x16x32_bf16(A1[kt], B[ct][kt], acc1[ct], 0, 0, 0);
        }
        #pragma unroll
        for (int ct = 0; ct < 4; ++ct) {
            int col = ocb + ct * 16 + m;
            #pragma unroll
            for (int i = 0; i < 4; ++i) {
                int row = row0 + q * 4 + i;
                OUT[(size_t)row * 128 + col] = f2bf(acc0[ct][i] + bias[ct]);
                if (two) OUT[(size_t)(row + 16) * 128 + col] = f2bf(acc1[ct][i] + bias[ct]);
            }
        }
    }
}

// ---------------- fused gather attention + residual + LN + relu ----------------
// 2 dst nodes/wave, 4 feats/lane, everything bf16 in. No-max softmax, x4 ILP
// (r8-proven body). h lives ONLY in bf16 (hB): residual read from hB, layers
// 0/1 write hB in place (own-row only — no cross-thread hazard); layer 2
// writes f32 to hf_out. No barriers, no LDS (r13's fused-mean barrier cost
// +19 us on layer 2 and was reverted).
__global__ __launch_bounds__(256) void agg_ln_kernel(const unsigned short* __restrict__ h_in,
                                                     const unsigned short* __restrict__ fsB,
                                                     const unsigned short* __restrict__ fdB,
                                                     const int* __restrict__ row_beg,
                                                     const int* __restrict__ counts,
                                                     const int* __restrict__ col,
                                                     const float* __restrict__ attn,
                                                     const float* __restrict__ ln_g,
                                                     const float* __restrict__ ln_b,
                                                     unsigned short* __restrict__ hb_out,
                                                     float* __restrict__ hf_out, int n) {
    int gwave = (blockIdx.x * blockDim.x + threadIdx.x) >> 6;
    int lane = threadIdx.x & 63;
    int half = lane >> 5;
    int sub = lane & 31;
    int node = gwave * 2 + half;
    if (node >= n) return;
    int f0 = 4 * sub;
    ushort4 ud = *(const ushort4*)(fdB + (size_t)node * 128 + f0);
    float4 fd4;
    fd4.x = bf2f(ud.x); fd4.y = bf2f(ud.y); fd4.z = bf2f(ud.z); fd4.w = bf2f(ud.w);
    ushort4 uh = *(const ushort4*)(h_in + (size_t)node * 128 + f0);
    float4 h4;
    h4.x = bf2f(uh.x); h4.y = bf2f(uh.y); h4.z = bf2f(uh.z); h4.w = bf2f(uh.w);
    const float4 a4 = *(const float4*)(attn + f0);
    int beg = row_beg[node], end = beg + counts[node] + 1;

    float z[4];
    float4 acc[4];
    #pragma unroll
    for (int k = 0; k < 4; ++k) {
        z[k] = 0.f;
        acc[k].x = 0.f; acc[k].y = 0.f; acc[k].z = 0.f; acc[k].w = 0.f;
    }

    int j = beg;
    for (; j + 3 < end; j += 4) {
        int s0 = col[j], s1 = col[j + 1], s2 = col[j + 2], s3 = col[j + 3];
        ushort4 u0 = *(const ushort4*)(fsB + (size_t)s0 * 128 + f0);
        ushort4 u1 = *(const ushort4*)(fsB + (size_t)s1 * 128 + f0);
        ushort4 u2 = *(const ushort4*)(fsB + (size_t)s2 * 128 + f0);
        ushort4 u3 = *(const ushort4*)(fsB + (size_t)s3 * 128 + f0);
        float4 v0, v1, v2, v3;
        v0.x = bf2f(u0.x); v0.y = bf2f(u0.y); v0.z = bf2f(u0.z); v0.w = bf2f(u0.w);
        v1.x = bf2f(u1.x); v1.y = bf2f(u1.y); v1.z = bf2f(u1.z); v1.w = bf2f(u1.w);
        v2.x = bf2f(u2.x); v2.y = bf2f(u2.y); v2.z = bf2f(u2.z); v2.w = bf2f(u2.w);
        v3.x = bf2f(u3.x); v3.y = bf2f(u3.y); v3.z = bf2f(u3.z); v3.w = bf2f(u3.w);
        float p0, p1, p2, p3;
        {
            float e0 = v0.x + fd4.x; e0 = fmaxf(e0, 0.2f * e0);
            float e1 = v0.y + fd4.y; e1 = fmaxf(e1, 0.2f * e1);
            float e2 = v0.z + fd4.z; e2 = fmaxf(e2, 0.2f * e2);
            float e3 = v0.w + fd4.w; e3 = fmaxf(e3, 0.2f * e3);
            p0 = e0 * a4.x + e1 * a4.y + e2 * a4.z + e3 * a4.w;
        }
        {
            float e0 = v1.x + fd4.x; e0 = fmaxf(e0, 0.2f * e0);
            float e1 = v1.y + fd4.y; e1 = fmaxf(e1, 0.2f * e1);
            float e2 = v1.z + fd4.z; e2 = fmaxf(e2, 0.2f * e2);
            float e3 = v1.w + fd4.w; e3 = fmaxf(e3, 0.2f * e3);
            p1 = e0 * a4.x + e1 * a4.y + e2 * a4.z + e3 * a4.w;
        }
        {
            float e0 = v2.x + fd4.x; e0 = fmaxf(e0, 0.2f * e0);
            float e1 = v2.y + fd4.y; e1 = fmaxf(e1, 0.2f * e1);
            float e2 = v2.z + fd4.z; e2 = fmaxf(e2, 0.2f * e2);
            float e3 = v2.w + fd4.w; e3 = fmaxf(e3, 0.2f * e3);
            p2 = e0 * a4.x + e1 * a4.y + e2 * a4.z + e3 * a4.w;
        }
        {
            float e0 = v3.x + fd4.x; e0 = fmaxf(e0, 0.2f * e0);
            float e1 = v3.y + fd4.y; e1 = fmaxf(e1, 0.2f * e1);
            float e2 = v3.z + fd4.z; e2 = fmaxf(e2, 0.2f * e2);
            float e3 = v3.w + fd4.w; e3 = fmaxf(e3, 0.2f * e3);
            p3 = e0 * a4.x + e1 * a4.y + e2 * a4.z + e3 * a4.w;
        }
        #pragma unroll
        for (int off = 1; off <= 4; off <<= 1) {
            p0 += __shfl_xor(p0, off);
            p1 += __shfl_xor(p1, off);
            p2 += __shfl_xor(p2, off);
            p3 += __shfl_xor(p3, off);
        }
        float w0 = __expf(p0), w1 = __expf(p1), w2 = __expf(p2), w3 = __expf(p3);
        z[0] += w0; z[1] += w1; z[2] += w2; z[3] += w3;
        acc[0].x += w0 * v0.x; acc[0].y += w0 * v0.y; acc[0].z += w0 * v0.z; acc[0].w += w0 * v0.w;
        acc[1].x += w1 * v1.x; acc[1].y += w1 * v1.y; acc[1].z += w1 * v1.z; acc[1].w += w1 * v1.w;
        acc[2].x += w2 * v2.x; acc[2].y += w2 * v2.y; acc[2].z += w2 * v2.z; acc[2].w += w2 * v2.w;
        acc[3].x += w3 * v3.x; acc[3].y += w3 * v3.y; acc[3].z += w3 * v3.z; acc[3].w += w3 * v3.w;
    }
    for (; j < end; ++j) {
        int s = col[j];
        ushort4 u = *(const ushort4*)(fsB + (size_t)s * 128 + f0);
        float4 v;
        v.x = bf2f(u.x); v.y = bf2f(u.y); v.z = bf2f(u.z); v.w = bf2f(u.w);
        float e0 = v.x + fd4.x; e0 = fmaxf(e0, 0.2f * e0);
        float e1 = v.y + fd4.y; e1 = fmaxf(e1, 0.2f * e1);
        float e2 = v.z + fd4.z; e2 = fmaxf(e2, 0.2f * e2);
        float e3 = v.w + fd4.w; e3 = fmaxf(e3, 0.2f * e3);
        float p = e0 * a4.x + e1 * a4.y + e2 * a4.z + e3 * a4.w;
        p += __shfl_xor(p, 1);
        p += __shfl_xor(p, 2);
        p += __shfl_xor(p, 4);
        float w = __expf(p);
        z[0] += w;
        acc[0].x += w * v.x; acc[0].y += w * v.y; acc[0].z += w * v.z; acc[0].w += w * v.w;
    }
    float zT = (z[0] + z[1]) + (z[2] + z[3]);
    float axT = (acc[0].x + acc[1].x) + (acc[2].x + acc[3].x);
    float ayT = (acc[0].y + acc[1].y) + (acc[2].y + acc[3].y);
    float azT = (acc[0].z + acc[1].z) + (acc[2].z + acc[3].z);
    float awT = (acc[0].w + acc[1].w) + (acc[2].w + acc[3].w);
    float inv = 1.0f / zT;
    float x0 = 2.f * h4.x + axT * inv;  // h + (aggr + h)
    float x1 = 2.f * h4.y + ayT * inv;
    float x2 = 2.f * h4.z + azT * inv;
    float x3 = 2.f * h4.w + awT * inv;
    float s = (x0 + x1) + (x2 + x3);
    #pragma unroll
    for (int off = 1; off <= 16; off <<= 1) s += __shfl_xor(s, off);
    float mean = s * (1.f / 128.f);
    float d0 = x0 - mean, d1 = x1 - mean, d2 = x2 - mean, d3 = x3 - mean;
    float v = (d0 * d0 + d1 * d1) + (d2 * d2 + d3 * d3);
    #pragma unroll
    for (int off = 1; off <= 16; off <<= 1) v += __shfl_xor(v, off);
    float rstd = rsqrtf(v * (1.f / 128.f) + 1e-5f);
    float4 g4 = *(const float4*)(ln_g + f0);
    float4 bb4 = *(const float4*)(ln_b + f0);
    float4 o;
    o.x = fmaxf(d0 * rstd * g4.x + bb4.x, 0.f);
    o.y = fmaxf(d1 * rstd * g4.y + bb4.y, 0.f);
    o.z = fmaxf(d2 * rstd * g4.z + bb4.z, 0.f);
    o.w = fmaxf(d3 * rstd * g4.w + bb4.w, 0.f);
    if (hf_out) {
        *(float4*)(hf_out + (size_t)node * 128 + f0) = o;
    } else {
        ushort4 ob;
        ob.x = f2bf(o.x); ob.y = f2bf(o.y); ob.z = f2bf(o.z); ob.w = f2bf(o.w);
        *(ushort4*)(hb_out + (size_t)node * 128 + f0) = ob;
    }
}

// ---------------- graph mean (two-stage, parallel) ----------------

__global__ __launch_bounds__(128) void mean1_kernel(const float* __restrict__ h,
                                                    float* __restrict__ partials, int n) {
    int c = threadIdx.x;
    float acc = 0.f;
    for (int r = blockIdx.x; r < n; r += gridDim.x)
        acc += h[(size_t)r * 128 + c];
    partials[blockIdx.x * 128 + c] = acc;
}

__global__ __launch_bounds__(1024) void mean2_kernel(const float* __restrict__ partials,
                                                     float* __restrict__ out, int nb, int n) {
    __shared__ float smem[8][128];
    int c = threadIdx.x & 127;
    int g = threadIdx.x >> 7;  // 0..7
    float acc = 0.f;
    for (int r = g; r < nb; r += 8)
        acc += partials[r * 128 + c];
    smem[g][c] = acc;
    __syncthreads();
    if (threadIdx.x < 128) {
        float s = 0.f;
        #pragma unroll
        for (int k = 0; k < 8; ++k) s += smem[k][c];
        out[c] = s * (1.f / n);
    }
}

extern "C" void kernel_launch(void* const* d_in, const int* in_sizes, int n_in,
                              void* d_out, int out_size, void* d_ws, size_t ws_size,
                              hipStream_t stream) {
    const float* node_feats = (const float*)d_in[0];
    const int* src = (const int*)d_in[1];
    const int* dst = (const int*)d_in[2];
    const float* W_in = (const float*)d_in[3];
    const float* b_in = (const float*)d_in[4];
    const float* W_src = (const float*)d_in[5];
    const float* b_src = (const float*)d_in[6];
    const float* W_dst = (const float*)d_in[7];
    const float* b_dst = (const float*)d_in[8];
    const float* attn = (const float*)d_in[9];
    const float* ln_g = (const float*)d_in[10];
    const float* ln_b = (const float*)d_in[11];
    float* out = (float*)d_out;

    const int N = NN;
    const int E = in_sizes[1];

    // workspace layout (hA eliminated — h lives in bf16 hB only)
    unsigned short* fsB = (unsigned short*)d_ws;      // N*128 bf16
    unsigned short* fdB = fsB + (size_t)N * 128;      // N*128 bf16
    unsigned short* hB = fdB + (size_t)N * 128;       // N*128 bf16
    unsigned short* xB = hB + (size_t)N * 128;        // N*64 bf16
    unsigned short* WtL = xB + (size_t)N * 64;        // 3*256*128 bf16
    unsigned short* WtIn = WtL + 3 * 32768;           // 128*64 bf16
    int* counts = (int*)(WtIn + 8192);                // N  (memset with total)
    int* total = counts + N;                          // 1
    int* row_beg = total + 1;                         // N
    int* rankb = row_beg + N;                         // E
    int* colb = rankb + E;                            // E+N
    float* partials = (float*)(colb + (E + N));       // 256*128

    // --- CSR build: one atomic pass (hist+rank), alloc, atomic-free scatter ---
    hipMemsetAsync(counts, 0, (size_t)(N + 1) * sizeof(int), stream);
    hist_rank_kernel<<<(E + 255) / 256, 256, 0, stream>>>(dst, counts, rankb, E);
    alloc_kernel<<<(N + 255) / 256, 256, 0, stream>>>(counts, row_beg, total, N);
    scatter_kernel<<<(E + N + 255) / 256, 256, 0, stream>>>(src, dst, rankb, row_beg,
                                                            counts, colb, E, N);

    // --- bf16 conversions (single fused kernel) ---
    convert_all_kernel<<<3541, 256, 0, stream>>>(node_feats, W_src, W_dst, W_in,
                                                 xB, WtL, WtIn);

    // --- input projection (MFMA, paired row-groups) ---
    in_proj_mfma<<<512, 256, 0, stream>>>(xB, WtIn, b_in, hB);

    // --- 3 GATv2 layers ---
    for (int l = 0; l < 3; ++l) {
        int last = (l == 2);
        dual_gemm_mfma<<<512, 256, 0, stream>>>(hB, WtL + (size_t)l * 32768,
                                                b_src + l * 128, b_dst + l * 128,
                                                fsB, fdB);
        agg_ln_kernel<<<(N + 7) / 8, 256, 0, stream>>>(hB, fsB, fdB, row_beg, counts, colb,
                                                       attn + l * 128, ln_g + l * 128,
                                                       ln_b + l * 128,
                                                       last ? nullptr : hB,
                                                       last ? (out + 128) : nullptr, N);
    }

    // --- graph mean into out[0:128] ---
    mean1_kernel<<<256, 128, 0, stream>>>(out + 128, partials, N);
    mean2_kernel<<<1, 1024, 0, stream>>>(partials, out, 256, N);
}

// Round 15
// 426.745 us; speedup vs baseline: 1.0038x; 1.0038x over previous
//
#include <hip/hip_runtime.h>
#include <hip/hip_bf16.h>

#define NN 50000

typedef short short8 __attribute__((ext_vector_type(8)));
typedef float f32x4 __attribute__((ext_vector_type(4)));

__device__ __forceinline__ unsigned short f2bf(float f) {
    unsigned int b = __float_as_uint(f);
    unsigned int r = (b + 0x7FFFu + ((b >> 16) & 1u)) >> 16;   // RNE
    return (unsigned short)r;
}
__device__ __forceinline__ float bf2f(unsigned short u) {
    return __uint_as_float((unsigned int)u << 16);
}

// ---------------- CSR build ----------------

__global__ void hist_rank_kernel(const int* __restrict__ dst, int* counts,
                                 int* __restrict__ rank, int E) {
    int i = blockIdx.x * blockDim.x + threadIdx.x;
    if (i < E) rank[i] = atomicAdd(&counts[dst[i]], 1);
}

__global__ __launch_bounds__(256) void alloc_kernel(const int* __restrict__ counts,
                                                    int* __restrict__ row_beg,
                                                    int* total, int n) {
    int i = blockIdx.x * blockDim.x + threadIdx.x;
    int lane = threadIdx.x & 63;
    int len = (i < n) ? (counts[i] + 1) : 0;
    int p = len;
    #pragma unroll
    for (int off = 1; off < 64; off <<= 1) {
        int t = __shfl_up(p, off);
        if (lane >= off) p += t;
    }
    int tot = __shfl(p, 63);
    int base = 0;
    if (lane == 63) base = atomicAdd(total, tot);
    base = __shfl(base, 63);
    if (i < n) row_beg[i] = base + p - len;
}

__global__ void scatter_kernel(const int* __restrict__ src, const int* __restrict__ dst,
                               const int* __restrict__ rank, const int* __restrict__ row_beg,
                               const int* __restrict__ counts,
                               int* __restrict__ col, int E, int n) {
    int i = blockIdx.x * blockDim.x + threadIdx.x;
    if (i >= E + n) return;
    if (i < E) {
        col[row_beg[dst[i]] + rank[i]] = src[i];
    } else {
        int v = i - E;
        col[row_beg[v] + counts[v]] = v;
    }
}

// ---------------- bf16 weight conversion (W_src|W_dst transposed, W_in) -------
// x is NOT pre-converted anymore — in_proj reads f32 x directly (saves a
// 12.8 MB round-trip through xB plus 3125 blocks of this kernel).
__global__ __launch_bounds__(256) void convert_w_kernel(const float* __restrict__ Ws,
                                                        const float* __restrict__ Wd,
                                                        const float* __restrict__ Win,
                                                        unsigned short* __restrict__ WtL,
                                                        unsigned short* __restrict__ WtIn) {
    int blk = blockIdx.x;
    if (blk < 384) {
        int e = blk * 256 + threadIdx.x;  // 0..98303
        int l = e >> 15;
        int r = e & 32767;
        int colc = r >> 7;
        int k = r & 127;
        float v = (colc < 128) ? Ws[l * 16384 + k * 128 + colc]
                               : Wd[l * 16384 + k * 128 + (colc - 128)];
        WtL[l * 32768 + colc * 128 + k] = f2bf(v);
    } else {
        int e = (blk - 384) * 256 + threadIdx.x;  // 0..8191
        int colc = e >> 6;
        int k = e & 63;
        WtIn[colc * 64 + k] = f2bf(Win[k * 128 + colc]);
    }
}

// ---------------- MFMA GEMMs ----------------
// Single row-group per iteration, 512 blocks, 4 waves/SIMD — the r11-measured
// best config (r12's 1024-block and r14's paired-rg variants both regressed:
// grid doubling under-amortizes the B-frag preload; pairing costs a resident
// wave via VGPR growth).
// in_proj: x_f32[N,64] @ W_in[64,128] + b -> hB (bf16), x converted inline.
__global__ __launch_bounds__(256, 4) void in_proj_mfma(const float* __restrict__ x,
                                                       const unsigned short* __restrict__ Wt,
                                                       const float* __restrict__ b,
                                                       unsigned short* __restrict__ hB) {
    int tid = threadIdx.x;
    int w = tid >> 6, l = tid & 63;
    int m = l & 15, q = l >> 4;
    short8 B[2][2];
    #pragma unroll
    for (int ct = 0; ct < 2; ++ct) {
        int col = w * 32 + ct * 16 + m;
        const unsigned short* wp = Wt + col * 64 + q * 8;
        #pragma unroll
        for (int kt = 0; kt < 2; ++kt) B[ct][kt] = *(const short8*)(wp + kt * 32);
    }
    float bias[2];
    #pragma unroll
    for (int ct = 0; ct < 2; ++ct) bias[ct] = b[w * 32 + ct * 16 + m];
    for (int rg = blockIdx.x; rg < NN / 16; rg += gridDim.x) {
        int row0 = rg * 16;
        const float* ap = x + (size_t)(row0 + m) * 64 + q * 8;
        short8 A[2];
        #pragma unroll
        for (int kt = 0; kt < 2; ++kt) {
            float4 f0 = *(const float4*)(ap + kt * 32);
            float4 f1 = *(const float4*)(ap + kt * 32 + 4);
            short8 a;
            a[0] = (short)f2bf(f0.x); a[1] = (short)f2bf(f0.y);
            a[2] = (short)f2bf(f0.z); a[3] = (short)f2bf(f0.w);
            a[4] = (short)f2bf(f1.x); a[5] = (short)f2bf(f1.y);
            a[6] = (short)f2bf(f1.z); a[7] = (short)f2bf(f1.w);
            A[kt] = a;
        }
        f32x4 acc[2];
        #pragma unroll
        for (int ct = 0; ct < 2; ++ct) acc[ct] = (f32x4){0.f, 0.f, 0.f, 0.f};
        #pragma unroll
        for (int kt = 0; kt < 2; ++kt)
            #pragma unroll
            for (int ct = 0; ct < 2; ++ct)
                acc[ct] = __builtin_amdgcn_mfma_f32_16x16x32_bf16(A[kt], B[ct][kt], acc[ct], 0, 0, 0);
        #pragma unroll
        for (int ct = 0; ct < 2; ++ct) {
            int col = w * 32 + ct * 16 + m;
            #pragma unroll
            for (int i = 0; i < 4; ++i) {
                int row = row0 + q * 4 + i;
                hB[(size_t)row * 128 + col] = f2bf(acc[ct][i] + bias[ct]);
            }
        }
    }
}

// dual: hB[N,128] @ [Ws|Wd][128,256] + bias -> fsB, fdB (bf16).
__global__ __launch_bounds__(256, 4) void dual_gemm_mfma(const unsigned short* __restrict__ hB,
                                                         const unsigned short* __restrict__ Wt,
                                                         const float* __restrict__ bs,
                                                         const float* __restrict__ bd,
                                                         unsigned short* __restrict__ fsB,
                                                         unsigned short* __restrict__ fdB) {
    int tid = threadIdx.x;
    int w = tid >> 6, l = tid & 63;
    int m = l & 15, q = l >> 4;
    short8 B[4][4];
    #pragma unroll
    for (int ct = 0; ct < 4; ++ct) {
        int col = w * 64 + ct * 16 + m;
        const unsigned short* wp = Wt + col * 128 + q * 8;
        #pragma unroll
        for (int kt = 0; kt < 4; ++kt) B[ct][kt] = *(const short8*)(wp + kt * 32);
    }
    const float* bptr = (w < 2) ? bs : bd;
    unsigned short* OUT = (w < 2) ? fsB : fdB;
    int ocb = (w * 64) & 127;
    float bias[4];
    #pragma unroll
    for (int ct = 0; ct < 4; ++ct) bias[ct] = bptr[ocb + ct * 16 + m];
    for (int rg = blockIdx.x; rg < NN / 16; rg += gridDim.x) {
        int row0 = rg * 16;
        const unsigned short* ap = hB + (size_t)(row0 + m) * 128 + q * 8;
        short8 A[4];
        #pragma unroll
        for (int kt = 0; kt < 4; ++kt) A[kt] = *(const short8*)(ap + kt * 32);
        f32x4 acc[4];
        #pragma unroll
        for (int ct = 0; ct < 4; ++ct) acc[ct] = (f32x4){0.f, 0.f, 0.f, 0.f};
        #pragma unroll
        for (int kt = 0; kt < 4; ++kt)
            #pragma unroll
            for (int ct = 0; ct < 4; ++ct)
                acc[ct] = __builtin_amdgcn_mfma_f32_16x16x32_bf16(A[kt], B[ct][kt], acc[ct], 0, 0, 0);
        #pragma unroll
        for (int ct = 0; ct < 4; ++ct) {
            int col = ocb + ct * 16 + m;
            #pragma unroll
            for (int i = 0; i < 4; ++i) {
                int row = row0 + q * 4 + i;
                OUT[(size_t)row * 128 + col] = f2bf(acc[ct][i] + bias[ct]);
            }
        }
    }
}

// ---------------- fused gather attention + residual + LN + relu ----------------
// 2 dst nodes/wave, 4 feats/lane, everything bf16 in. No-max softmax, x4 ILP
// (r8-proven body, VGPR ~44 — its measured floor is ~55 us across 6 variants).
// h lives ONLY in bf16 (hB): layers 0/1 write hB in place (own-row only);
// layer 2 writes f32 to hf_out.
__global__ __launch_bounds__(256) void agg_ln_kernel(const unsigned short* __restrict__ h_in,
                                                     const unsigned short* __restrict__ fsB,
                                                     const unsigned short* __restrict__ fdB,
                                                     const int* __restrict__ row_beg,
                                                     const int* __restrict__ counts,
                                                     const int* __restrict__ col,
                                                     const float* __restrict__ attn,
                                                     const float* __restrict__ ln_g,
                                                     const float* __restrict__ ln_b,
                                                     unsigned short* __restrict__ hb_out,
                                                     float* __restrict__ hf_out, int n) {
    int gwave = (blockIdx.x * blockDim.x + threadIdx.x) >> 6;
    int lane = threadIdx.x & 63;
    int half = lane >> 5;
    int sub = lane & 31;
    int node = gwave * 2 + half;
    if (node >= n) return;
    int f0 = 4 * sub;
    ushort4 ud = *(const ushort4*)(fdB + (size_t)node * 128 + f0);
    float4 fd4;
    fd4.x = bf2f(ud.x); fd4.y = bf2f(ud.y); fd4.z = bf2f(ud.z); fd4.w = bf2f(ud.w);
    ushort4 uh = *(const ushort4*)(h_in + (size_t)node * 128 + f0);
    float4 h4;
    h4.x = bf2f(uh.x); h4.y = bf2f(uh.y); h4.z = bf2f(uh.z); h4.w = bf2f(uh.w);
    const float4 a4 = *(const float4*)(attn + f0);
    int beg = row_beg[node], end = beg + counts[node] + 1;

    float z[4];
    float4 acc[4];
    #pragma unroll
    for (int k = 0; k < 4; ++k) {
        z[k] = 0.f;
        acc[k].x = 0.f; acc[k].y = 0.f; acc[k].z = 0.f; acc[k].w = 0.f;
    }

    int j = beg;
    for (; j + 3 < end; j += 4) {
        int s0 = col[j], s1 = col[j + 1], s2 = col[j + 2], s3 = col[j + 3];
        ushort4 u0 = *(const ushort4*)(fsB + (size_t)s0 * 128 + f0);
        ushort4 u1 = *(const ushort4*)(fsB + (size_t)s1 * 128 + f0);
        ushort4 u2 = *(const ushort4*)(fsB + (size_t)s2 * 128 + f0);
        ushort4 u3 = *(const ushort4*)(fsB + (size_t)s3 * 128 + f0);
        float4 v0, v1, v2, v3;
        v0.x = bf2f(u0.x); v0.y = bf2f(u0.y); v0.z = bf2f(u0.z); v0.w = bf2f(u0.w);
        v1.x = bf2f(u1.x); v1.y = bf2f(u1.y); v1.z = bf2f(u1.z); v1.w = bf2f(u1.w);
        v2.x = bf2f(u2.x); v2.y = bf2f(u2.y); v2.z = bf2f(u2.z); v2.w = bf2f(u2.w);
        v3.x = bf2f(u3.x); v3.y = bf2f(u3.y); v3.z = bf2f(u3.z); v3.w = bf2f(u3.w);
        float p0, p1, p2, p3;
        {
            float e0 = v0.x + fd4.x; e0 = fmaxf(e0, 0.2f * e0);
            float e1 = v0.y + fd4.y; e1 = fmaxf(e1, 0.2f * e1);
            float e2 = v0.z + fd4.z; e2 = fmaxf(e2, 0.2f * e2);
            float e3 = v0.w + fd4.w; e3 = fmaxf(e3, 0.2f * e3);
            p0 = e0 * a4.x + e1 * a4.y + e2 * a4.z + e3 * a4.w;
        }
        {
            float e0 = v1.x + fd4.x; e0 = fmaxf(e0, 0.2f * e0);
            float e1 = v1.y + fd4.y; e1 = fmaxf(e1, 0.2f * e1);
            float e2 = v1.z + fd4.z; e2 = fmaxf(e2, 0.2f * e2);
            float e3 = v1.w + fd4.w; e3 = fmaxf(e3, 0.2f * e3);
            p1 = e0 * a4.x + e1 * a4.y + e2 * a4.z + e3 * a4.w;
        }
        {
            float e0 = v2.x + fd4.x; e0 = fmaxf(e0, 0.2f * e0);
            float e1 = v2.y + fd4.y; e1 = fmaxf(e1, 0.2f * e1);
            float e2 = v2.z + fd4.z; e2 = fmaxf(e2, 0.2f * e2);
            float e3 = v2.w + fd4.w; e3 = fmaxf(e3, 0.2f * e3);
            p2 = e0 * a4.x + e1 * a4.y + e2 * a4.z + e3 * a4.w;
        }
        {
            float e0 = v3.x + fd4.x; e0 = fmaxf(e0, 0.2f * e0);
            float e1 = v3.y + fd4.y; e1 = fmaxf(e1, 0.2f * e1);
            float e2 = v3.z + fd4.z; e2 = fmaxf(e2, 0.2f * e2);
            float e3 = v3.w + fd4.w; e3 = fmaxf(e3, 0.2f * e3);
            p3 = e0 * a4.x + e1 * a4.y + e2 * a4.z + e3 * a4.w;
        }
        #pragma unroll
        for (int off = 1; off <= 4; off <<= 1) {
            p0 += __shfl_xor(p0, off);
            p1 += __shfl_xor(p1, off);
            p2 += __shfl_xor(p2, off);
            p3 += __shfl_xor(p3, off);
        }
        float w0 = __expf(p0), w1 = __expf(p1), w2 = __expf(p2), w3 = __expf(p3);
        z[0] += w0; z[1] += w1; z[2] += w2; z[3] += w3;
        acc[0].x += w0 * v0.x; acc[0].y += w0 * v0.y; acc[0].z += w0 * v0.z; acc[0].w += w0 * v0.w;
        acc[1].x += w1 * v1.x; acc[1].y += w1 * v1.y; acc[1].z += w1 * v1.z; acc[1].w += w1 * v1.w;
        acc[2].x += w2 * v2.x; acc[2].y += w2 * v2.y; acc[2].z += w2 * v2.z; acc[2].w += w2 * v2.w;
        acc[3].x += w3 * v3.x; acc[3].y += w3 * v3.y; acc[3].z += w3 * v3.z; acc[3].w += w3 * v3.w;
    }
    for (; j < end; ++j) {
        int s = col[j];
        ushort4 u = *(const ushort4*)(fsB + (size_t)s * 128 + f0);
        float4 v;
        v.x = bf2f(u.x); v.y = bf2f(u.y); v.z = bf2f(u.z); v.w = bf2f(u.w);
        float e0 = v.x + fd4.x; e0 = fmaxf(e0, 0.2f * e0);
        float e1 = v.y + fd4.y; e1 = fmaxf(e1, 0.2f * e1);
        float e2 = v.z + fd4.z; e2 = fmaxf(e2, 0.2f * e2);
        float e3 = v.w + fd4.w; e3 = fmaxf(e3, 0.2f * e3);
        float p = e0 * a4.x + e1 * a4.y + e2 * a4.z + e3 * a4.w;
        p += __shfl_xor(p, 1);
        p += __shfl_xor(p, 2);
        p += __shfl_xor(p, 4);
        float w = __expf(p);
        z[0] += w;
        acc[0].x += w * v.x; acc[0].y += w * v.y; acc[0].z += w * v.z; acc[0].w += w * v.w;
    }
    float zT = (z[0] + z[1]) + (z[2] + z[3]);
    float axT = (acc[0].x + acc[1].x) + (acc[2].x + acc[3].x);
    float ayT = (acc[0].y + acc[1].y) + (acc[2].y + acc[3].y);
    float azT = (acc[0].z + acc[1].z) + (acc[2].z + acc[3].z);
    float awT = (acc[0].w + acc[1].w) + (acc[2].w + acc[3].w);
    float inv = 1.0f / zT;
    float x0 = 2.f * h4.x + axT * inv;  // h + (aggr + h)
    float x1 = 2.f * h4.y + ayT * inv;
    float x2 = 2.f * h4.z + azT * inv;
    float x3 = 2.f * h4.w + awT * inv;
    float s = (x0 + x1) + (x2 + x3);
    #pragma unroll
    for (int off = 1; off <= 16; off <<= 1) s += __shfl_xor(s, off);
    float mean = s * (1.f / 128.f);
    float d0 = x0 - mean, d1 = x1 - mean, d2 = x2 - mean, d3 = x3 - mean;
    float v = (d0 * d0 + d1 * d1) + (d2 * d2 + d3 * d3);
    #pragma unroll
    for (int off = 1; off <= 16; off <<= 1) v += __shfl_xor(v, off);
    float rstd = rsqrtf(v * (1.f / 128.f) + 1e-5f);
    float4 g4 = *(const float4*)(ln_g + f0);
    float4 bb4 = *(const float4*)(ln_b + f0);
    float4 o;
    o.x = fmaxf(d0 * rstd * g4.x + bb4.x, 0.f);
    o.y = fmaxf(d1 * rstd * g4.y + bb4.y, 0.f);
    o.z = fmaxf(d2 * rstd * g4.z + bb4.z, 0.f);
    o.w = fmaxf(d3 * rstd * g4.w + bb4.w, 0.f);
    if (hf_out) {
        *(float4*)(hf_out + (size_t)node * 128 + f0) = o;
    } else {
        ushort4 ob;
        ob.x = f2bf(o.x); ob.y = f2bf(o.y); ob.z = f2bf(o.z); ob.w = f2bf(o.w);
        *(ushort4*)(hb_out + (size_t)node * 128 + f0) = ob;
    }
}

// ---------------- graph mean (two-stage, parallel) ----------------

__global__ __launch_bounds__(128) void mean1_kernel(const float* __restrict__ h,
                                                    float* __restrict__ partials, int n) {
    int c = threadIdx.x;
    float acc = 0.f;
    for (int r = blockIdx.x; r < n; r += gridDim.x)
        acc += h[(size_t)r * 128 + c];
    partials[blockIdx.x * 128 + c] = acc;
}

__global__ __launch_bounds__(1024) void mean2_kernel(const float* __restrict__ partials,
                                                     float* __restrict__ out, int nb, int n) {
    __shared__ float smem[8][128];
    int c = threadIdx.x & 127;
    int g = threadIdx.x >> 7;  // 0..7
    float acc = 0.f;
    for (int r = g; r < nb; r += 8)
        acc += partials[r * 128 + c];
    smem[g][c] = acc;
    __syncthreads();
    if (threadIdx.x < 128) {
        float s = 0.f;
        #pragma unroll
        for (int k = 0; k < 8; ++k) s += smem[k][c];
        out[c] = s * (1.f / n);
    }
}

extern "C" void kernel_launch(void* const* d_in, const int* in_sizes, int n_in,
                              void* d_out, int out_size, void* d_ws, size_t ws_size,
                              hipStream_t stream) {
    const float* node_feats = (const float*)d_in[0];
    const int* src = (const int*)d_in[1];
    const int* dst = (const int*)d_in[2];
    const float* W_in = (const float*)d_in[3];
    const float* b_in = (const float*)d_in[4];
    const float* W_src = (const float*)d_in[5];
    const float* b_src = (const float*)d_in[6];
    const float* W_dst = (const float*)d_in[7];
    const float* b_dst = (const float*)d_in[8];
    const float* attn = (const float*)d_in[9];
    const float* ln_g = (const float*)d_in[10];
    const float* ln_b = (const float*)d_in[11];
    float* out = (float*)d_out;

    const int N = NN;
    const int E = in_sizes[1];

    // workspace layout (h bf16-only; no xB — in_proj reads x directly)
    unsigned short* fsB = (unsigned short*)d_ws;      // N*128 bf16
    unsigned short* fdB = fsB + (size_t)N * 128;      // N*128 bf16
    unsigned short* hB = fdB + (size_t)N * 128;       // N*128 bf16
    unsigned short* WtL = hB + (size_t)N * 128;       // 3*256*128 bf16
    unsigned short* WtIn = WtL + 3 * 32768;           // 128*64 bf16
    int* counts = (int*)(WtIn + 8192);                // N  (memset with total)
    int* total = counts + N;                          // 1
    int* row_beg = total + 1;                         // N
    int* rankb = row_beg + N;                         // E
    int* colb = rankb + E;                            // E+N
    float* partials = (float*)(colb + (E + N));       // 256*128

    // --- CSR build: one atomic pass (hist+rank), alloc, atomic-free scatter ---
    hipMemsetAsync(counts, 0, (size_t)(N + 1) * sizeof(int), stream);
    hist_rank_kernel<<<(E + 255) / 256, 256, 0, stream>>>(dst, counts, rankb, E);
    alloc_kernel<<<(N + 255) / 256, 256, 0, stream>>>(counts, row_beg, total, N);
    scatter_kernel<<<(E + N + 255) / 256, 256, 0, stream>>>(src, dst, rankb, row_beg,
                                                            counts, colb, E, N);

    // --- bf16 weight conversion ---
    convert_w_kernel<<<416, 256, 0, stream>>>(W_src, W_dst, W_in, WtL, WtIn);

    // --- input projection (MFMA, inline f32->bf16 A-frags) ---
    in_proj_mfma<<<512, 256, 0, stream>>>(node_feats, WtIn, b_in, hB);

    // --- 3 GATv2 layers ---
    for (int l = 0; l < 3; ++l) {
        int last = (l == 2);
        dual_gemm_mfma<<<512, 256, 0, stream>>>(hB, WtL + (size_t)l * 32768,
                                                b_src + l * 128, b_dst + l * 128,
                                                fsB, fdB);
        agg_ln_kernel<<<(N + 7) / 8, 256, 0, stream>>>(hB, fsB, fdB, row_beg, counts, colb,
                                                       attn + l * 128, ln_g + l * 128,
                                                       ln_b + l * 128,
                                                       last ? nullptr : hB,
                                                       last ? (out + 128) : nullptr, N);
    }

    // --- graph mean into out[0:128] ---
    mean1_kernel<<<256, 128, 0, stream>>>(out + 128, partials, N);
    mean2_kernel<<<1, 1024, 0, stream>>>(partials, out, 256, N);
}

// Round 16
// 425.875 us; speedup vs baseline: 1.0058x; 1.0020x over previous
//
#include <hip/hip_runtime.h>
#include <hip/hip_bf16.h>

#define NN 50000

typedef short short8 __attribute__((ext_vector_type(8)));
typedef float f32x4 __attribute__((ext_vector_type(4)));

#define GLOBAL_AS __attribute__((address_space(1)))
#define LDS_AS __attribute__((address_space(3)))

__device__ __forceinline__ unsigned short f2bf(float f) {
    unsigned int b = __float_as_uint(f);
    unsigned int r = (b + 0x7FFFu + ((b >> 16) & 1u)) >> 16;   // RNE
    return (unsigned short)r;
}
__device__ __forceinline__ float bf2f(unsigned short u) {
    return __uint_as_float((unsigned int)u << 16);
}

// ---------------- CSR build ----------------

__global__ void hist_rank_kernel(const int* __restrict__ dst, int* counts,
                                 int* __restrict__ rank, int E) {
    int i = blockIdx.x * blockDim.x + threadIdx.x;
    if (i < E) rank[i] = atomicAdd(&counts[dst[i]], 1);
}

__global__ __launch_bounds__(256) void alloc_kernel(const int* __restrict__ counts,
                                                    int* __restrict__ row_beg,
                                                    int* total, int n) {
    int i = blockIdx.x * blockDim.x + threadIdx.x;
    int lane = threadIdx.x & 63;
    int len = (i < n) ? (counts[i] + 1) : 0;
    int p = len;
    #pragma unroll
    for (int off = 1; off < 64; off <<= 1) {
        int t = __shfl_up(p, off);
        if (lane >= off) p += t;
    }
    int tot = __shfl(p, 63);
    int base = 0;
    if (lane == 63) base = atomicAdd(total, tot);
    base = __shfl(base, 63);
    if (i < n) row_beg[i] = base + p - len;
}

__global__ void scatter_kernel(const int* __restrict__ src, const int* __restrict__ dst,
                               const int* __restrict__ rank, const int* __restrict__ row_beg,
                               const int* __restrict__ counts,
                               int* __restrict__ col, int E, int n) {
    int i = blockIdx.x * blockDim.x + threadIdx.x;
    if (i >= E + n) return;
    if (i < E) {
        col[row_beg[dst[i]] + rank[i]] = src[i];
    } else {
        int v = i - E;
        col[row_beg[v] + counts[v]] = v;
    }
}

// ---------------- bf16 weight conversion ----------------
__global__ __launch_bounds__(256) void convert_w_kernel(const float* __restrict__ Ws,
                                                        const float* __restrict__ Wd,
                                                        const float* __restrict__ Win,
                                                        unsigned short* __restrict__ WtL,
                                                        unsigned short* __restrict__ WtIn) {
    int blk = blockIdx.x;
    if (blk < 384) {
        int e = blk * 256 + threadIdx.x;  // 0..98303
        int l = e >> 15;
        int r = e & 32767;
        int colc = r >> 7;
        int k = r & 127;
        float v = (colc < 128) ? Ws[l * 16384 + k * 128 + colc]
                               : Wd[l * 16384 + k * 128 + (colc - 128)];
        WtL[l * 32768 + colc * 128 + k] = f2bf(v);
    } else {
        int e = (blk - 384) * 256 + threadIdx.x;  // 0..8191
        int colc = e >> 6;
        int k = e & 63;
        WtIn[colc * 64 + k] = f2bf(Win[k * 128 + colc]);
    }
}

// ---------------- MFMA GEMMs ----------------
// in_proj: x_f32[N,64] @ W_in[64,128] + b -> hB (bf16), x converted inline.
__global__ __launch_bounds__(256, 4) void in_proj_mfma(const float* __restrict__ x,
                                                       const unsigned short* __restrict__ Wt,
                                                       const float* __restrict__ b,
                                                       unsigned short* __restrict__ hB) {
    int tid = threadIdx.x;
    int w = tid >> 6, l = tid & 63;
    int m = l & 15, q = l >> 4;
    short8 B[2][2];
    #pragma unroll
    for (int ct = 0; ct < 2; ++ct) {
        int col = w * 32 + ct * 16 + m;
        const unsigned short* wp = Wt + col * 64 + q * 8;
        #pragma unroll
        for (int kt = 0; kt < 2; ++kt) B[ct][kt] = *(const short8*)(wp + kt * 32);
    }
    float bias[2];
    #pragma unroll
    for (int ct = 0; ct < 2; ++ct) bias[ct] = b[w * 32 + ct * 16 + m];
    for (int rg = blockIdx.x; rg < NN / 16; rg += gridDim.x) {
        int row0 = rg * 16;
        const float* ap = x + (size_t)(row0 + m) * 64 + q * 8;
        short8 A[2];
        #pragma unroll
        for (int kt = 0; kt < 2; ++kt) {
            float4 f0 = *(const float4*)(ap + kt * 32);
            float4 f1 = *(const float4*)(ap + kt * 32 + 4);
            short8 a;
            a[0] = (short)f2bf(f0.x); a[1] = (short)f2bf(f0.y);
            a[2] = (short)f2bf(f0.z); a[3] = (short)f2bf(f0.w);
            a[4] = (short)f2bf(f1.x); a[5] = (short)f2bf(f1.y);
            a[6] = (short)f2bf(f1.z); a[7] = (short)f2bf(f1.w);
            A[kt] = a;
        }
        f32x4 acc[2];
        #pragma unroll
        for (int ct = 0; ct < 2; ++ct) acc[ct] = (f32x4){0.f, 0.f, 0.f, 0.f};
        #pragma unroll
        for (int kt = 0; kt < 2; ++kt)
            #pragma unroll
            for (int ct = 0; ct < 2; ++ct)
                acc[ct] = __builtin_amdgcn_mfma_f32_16x16x32_bf16(A[kt], B[ct][kt], acc[ct], 0, 0, 0);
        #pragma unroll
        for (int ct = 0; ct < 2; ++ct) {
            int col = w * 32 + ct * 16 + m;
            #pragma unroll
            for (int i = 0; i < 4; ++i) {
                int row = row0 + q * 4 + i;
                hB[(size_t)row * 128 + col] = f2bf(acc[ct][i] + bias[ct]);
            }
        }
    }
}

// dual v2: LDS-staged A-tile. One block = one 64-row tile; A (64x128 bf16 =
// 16 KB) staged via global_load_lds width-16 (linear lane-contiguous dest),
// then each wave computes its 64 cols over 4 row-groups with ds_read_b128
// A-frags. Kills the 4x redundant global A reads + ~600cy per-iteration
// latency exposure of the register-direct version (~45 us, ~82 TF).
__global__ __launch_bounds__(256, 4) void dual_gemm_mfma(const unsigned short* __restrict__ hB,
                                                         const unsigned short* __restrict__ Wt,
                                                         const float* __restrict__ bs,
                                                         const float* __restrict__ bd,
                                                         unsigned short* __restrict__ fsB,
                                                         unsigned short* __restrict__ fdB) {
    __shared__ unsigned short Atile[64 * 128];   // 16 KB
    int tid = threadIdx.x;
    int w = tid >> 6, l = tid & 63;
    int m = l & 15, q = l >> 4;
    short8 B[4][4];
    #pragma unroll
    for (int ct = 0; ct < 4; ++ct) {
        int col = w * 64 + ct * 16 + m;
        const unsigned short* wp = Wt + col * 128 + q * 8;
        #pragma unroll
        for (int kt = 0; kt < 4; ++kt) B[ct][kt] = *(const short8*)(wp + kt * 32);
    }
    const float* bptr = (w < 2) ? bs : bd;
    unsigned short* OUT = (w < 2) ? fsB : fdB;
    int ocb = (w * 64) & 127;
    float bias[4];
    #pragma unroll
    for (int ct = 0; ct < 4; ++ct) bias[ct] = bptr[ocb + ct * 16 + m];

    const int NT = (NN + 63) / 64;   // 782 tiles (last partial; staging may
                                     // over-read into adjacent ws buffers — safe)
    for (int t = blockIdx.x; t < NT; t += gridDim.x) {
        int row0 = t * 64;
        const char* gsrc = (const char*)(hB + (size_t)row0 * 128);
        #pragma unroll
        for (int c = 0; c < 4; ++c) {
            int off = c * 4096 + tid * 16;
            __builtin_amdgcn_global_load_lds((const GLOBAL_AS void*)(gsrc + off),
                                             (LDS_AS void*)((char*)Atile + off), 16, 0, 0);
        }
        __syncthreads();
        #pragma unroll
        for (int rg = 0; rg < 4; ++rg) {
            const unsigned short* ap = Atile + (rg * 16 + m) * 128 + q * 8;
            short8 A[4];
            #pragma unroll
            for (int kt = 0; kt < 4; ++kt) A[kt] = *(const short8*)(ap + kt * 32);
            f32x4 acc[4];
            #pragma unroll
            for (int ct = 0; ct < 4; ++ct) acc[ct] = (f32x4){0.f, 0.f, 0.f, 0.f};
            #pragma unroll
            for (int kt = 0; kt < 4; ++kt)
                #pragma unroll
                for (int ct = 0; ct < 4; ++ct)
                    acc[ct] = __builtin_amdgcn_mfma_f32_16x16x32_bf16(A[kt], B[ct][kt], acc[ct], 0, 0, 0);
            #pragma unroll
            for (int ct = 0; ct < 4; ++ct) {
                int col = ocb + ct * 16 + m;
                #pragma unroll
                for (int i = 0; i < 4; ++i) {
                    int row = row0 + rg * 16 + q * 4 + i;
                    if (row < NN) OUT[(size_t)row * 128 + col] = f2bf(acc[ct][i] + bias[ct]);
                }
            }
        }
        __syncthreads();
    }
}

// ---------------- fused gather attention + residual + LN + relu ----------------
// 2 dst nodes/wave, 4 feats/lane, everything bf16 in. No-max softmax, x4 ILP
// (r8-proven body, measured floor ~55 us across 6 variants). h lives ONLY in
// bf16 (hB); layer 2 writes f32 to hf_out.
__global__ __launch_bounds__(256) void agg_ln_kernel(const unsigned short* __restrict__ h_in,
                                                     const unsigned short* __restrict__ fsB,
                                                     const unsigned short* __restrict__ fdB,
                                                     const int* __restrict__ row_beg,
                                                     const int* __restrict__ counts,
                                                     const int* __restrict__ col,
                                                     const float* __restrict__ attn,
                                                     const float* __restrict__ ln_g,
                                                     const float* __restrict__ ln_b,
                                                     unsigned short* __restrict__ hb_out,
                                                     float* __restrict__ hf_out, int n) {
    int gwave = (blockIdx.x * blockDim.x + threadIdx.x) >> 6;
    int lane = threadIdx.x & 63;
    int half = lane >> 5;
    int sub = lane & 31;
    int node = gwave * 2 + half;
    if (node >= n) return;
    int f0 = 4 * sub;
    ushort4 ud = *(const ushort4*)(fdB + (size_t)node * 128 + f0);
    float4 fd4;
    fd4.x = bf2f(ud.x); fd4.y = bf2f(ud.y); fd4.z = bf2f(ud.z); fd4.w = bf2f(ud.w);
    ushort4 uh = *(const ushort4*)(h_in + (size_t)node * 128 + f0);
    float4 h4;
    h4.x = bf2f(uh.x); h4.y = bf2f(uh.y); h4.z = bf2f(uh.z); h4.w = bf2f(uh.w);
    const float4 a4 = *(const float4*)(attn + f0);
    int beg = row_beg[node], end = beg + counts[node] + 1;

    float z[4];
    float4 acc[4];
    #pragma unroll
    for (int k = 0; k < 4; ++k) {
        z[k] = 0.f;
        acc[k].x = 0.f; acc[k].y = 0.f; acc[k].z = 0.f; acc[k].w = 0.f;
    }

    int j = beg;
    for (; j + 3 < end; j += 4) {
        int s0 = col[j], s1 = col[j + 1], s2 = col[j + 2], s3 = col[j + 3];
        ushort4 u0 = *(const ushort4*)(fsB + (size_t)s0 * 128 + f0);
        ushort4 u1 = *(const ushort4*)(fsB + (size_t)s1 * 128 + f0);
        ushort4 u2 = *(const ushort4*)(fsB + (size_t)s2 * 128 + f0);
        ushort4 u3 = *(const ushort4*)(fsB + (size_t)s3 * 128 + f0);
        float4 v0, v1, v2, v3;
        v0.x = bf2f(u0.x); v0.y = bf2f(u0.y); v0.z = bf2f(u0.z); v0.w = bf2f(u0.w);
        v1.x = bf2f(u1.x); v1.y = bf2f(u1.y); v1.z = bf2f(u1.z); v1.w = bf2f(u1.w);
        v2.x = bf2f(u2.x); v2.y = bf2f(u2.y); v2.z = bf2f(u2.z); v2.w = bf2f(u2.w);
        v3.x = bf2f(u3.x); v3.y = bf2f(u3.y); v3.z = bf2f(u3.z); v3.w = bf2f(u3.w);
        float p0, p1, p2, p3;
        {
            float e0 = v0.x + fd4.x; e0 = fmaxf(e0, 0.2f * e0);
            float e1 = v0.y + fd4.y; e1 = fmaxf(e1, 0.2f * e1);
            float e2 = v0.z + fd4.z; e2 = fmaxf(e2, 0.2f * e2);
            float e3 = v0.w + fd4.w; e3 = fmaxf(e3, 0.2f * e3);
            p0 = e0 * a4.x + e1 * a4.y + e2 * a4.z + e3 * a4.w;
        }
        {
            float e0 = v1.x + fd4.x; e0 = fmaxf(e0, 0.2f * e0);
            float e1 = v1.y + fd4.y; e1 = fmaxf(e1, 0.2f * e1);
            float e2 = v1.z + fd4.z; e2 = fmaxf(e2, 0.2f * e2);
            float e3 = v1.w + fd4.w; e3 = fmaxf(e3, 0.2f * e3);
            p1 = e0 * a4.x + e1 * a4.y + e2 * a4.z + e3 * a4.w;
        }
        {
            float e0 = v2.x + fd4.x; e0 = fmaxf(e0, 0.2f * e0);
            float e1 = v2.y + fd4.y; e1 = fmaxf(e1, 0.2f * e1);
            float e2 = v2.z + fd4.z; e2 = fmaxf(e2, 0.2f * e2);
            float e3 = v2.w + fd4.w; e3 = fmaxf(e3, 0.2f * e3);
            p2 = e0 * a4.x + e1 * a4.y + e2 * a4.z + e3 * a4.w;
        }
        {
            float e0 = v3.x + fd4.x; e0 = fmaxf(e0, 0.2f * e0);
            float e1 = v3.y + fd4.y; e1 = fmaxf(e1, 0.2f * e1);
            float e2 = v3.z + fd4.z; e2 = fmaxf(e2, 0.2f * e2);
            float e3 = v3.w + fd4.w; e3 = fmaxf(e3, 0.2f * e3);
            p3 = e0 * a4.x + e1 * a4.y + e2 * a4.z + e3 * a4.w;
        }
        #pragma unroll
        for (int off = 1; off <= 4; off <<= 1) {
            p0 += __shfl_xor(p0, off);
            p1 += __shfl_xor(p1, off);
            p2 += __shfl_xor(p2, off);
            p3 += __shfl_xor(p3, off);
        }
        float w0 = __expf(p0), w1 = __expf(p1), w2 = __expf(p2), w3 = __expf(p3);
        z[0] += w0; z[1] += w1; z[2] += w2; z[3] += w3;
        acc[0].x += w0 * v0.x; acc[0].y += w0 * v0.y; acc[0].z += w0 * v0.z; acc[0].w += w0 * v0.w;
        acc[1].x += w1 * v1.x; acc[1].y += w1 * v1.y; acc[1].z += w1 * v1.z; acc[1].w += w1 * v1.w;
        acc[2].x += w2 * v2.x; acc[2].y += w2 * v2.y; acc[2].z += w2 * v2.z; acc[2].w += w2 * v2.w;
        acc[3].x += w3 * v3.x; acc[3].y += w3 * v3.y; acc[3].z += w3 * v3.z; acc[3].w += w3 * v3.w;
    }
    for (; j < end; ++j) {
        int s = col[j];
        ushort4 u = *(const ushort4*)(fsB + (size_t)s * 128 + f0);
        float4 v;
        v.x = bf2f(u.x); v.y = bf2f(u.y); v.z = bf2f(u.z); v.w = bf2f(u.w);
        float e0 = v.x + fd4.x; e0 = fmaxf(e0, 0.2f * e0);
        float e1 = v.y + fd4.y; e1 = fmaxf(e1, 0.2f * e1);
        float e2 = v.z + fd4.z; e2 = fmaxf(e2, 0.2f * e2);
        float e3 = v.w + fd4.w; e3 = fmaxf(e3, 0.2f * e3);
        float p = e0 * a4.x + e1 * a4.y + e2 * a4.z + e3 * a4.w;
        p += __shfl_xor(p, 1);
        p += __shfl_xor(p, 2);
        p += __shfl_xor(p, 4);
        float w = __expf(p);
        z[0] += w;
        acc[0].x += w * v.x; acc[0].y += w * v.y; acc[0].z += w * v.z; acc[0].w += w * v.w;
    }
    float zT = (z[0] + z[1]) + (z[2] + z[3]);
    float axT = (acc[0].x + acc[1].x) + (acc[2].x + acc[3].x);
    float ayT = (acc[0].y + acc[1].y) + (acc[2].y + acc[3].y);
    float azT = (acc[0].z + acc[1].z) + (acc[2].z + acc[3].z);
    float awT = (acc[0].w + acc[1].w) + (acc[2].w + acc[3].w);
    float inv = 1.0f / zT;
    float x0 = 2.f * h4.x + axT * inv;  // h + (aggr + h)
    float x1 = 2.f * h4.y + ayT * inv;
    float x2 = 2.f * h4.z + azT * inv;
    float x3 = 2.f * h4.w + awT * inv;
    float s = (x0 + x1) + (x2 + x3);
    #pragma unroll
    for (int off = 1; off <= 16; off <<= 1) s += __shfl_xor(s, off);
    float mean = s * (1.f / 128.f);
    float d0 = x0 - mean, d1 = x1 - mean, d2 = x2 - mean, d3 = x3 - mean;
    float v = (d0 * d0 + d1 * d1) + (d2 * d2 + d3 * d3);
    #pragma unroll
    for (int off = 1; off <= 16; off <<= 1) v += __shfl_xor(v, off);
    float rstd = rsqrtf(v * (1.f / 128.f) + 1e-5f);
    float4 g4 = *(const float4*)(ln_g + f0);
    float4 bb4 = *(const float4*)(ln_b + f0);
    float4 o;
    o.x = fmaxf(d0 * rstd * g4.x + bb4.x, 0.f);
    o.y = fmaxf(d1 * rstd * g4.y + bb4.y, 0.f);
    o.z = fmaxf(d2 * rstd * g4.z + bb4.z, 0.f);
    o.w = fmaxf(d3 * rstd * g4.w + bb4.w, 0.f);
    if (hf_out) {
        *(float4*)(hf_out + (size_t)node * 128 + f0) = o;
    } else {
        ushort4 ob;
        ob.x = f2bf(o.x); ob.y = f2bf(o.y); ob.z = f2bf(o.z); ob.w = f2bf(o.w);
        *(ushort4*)(hb_out + (size_t)node * 128 + f0) = ob;
    }
}

// ---------------- graph mean (two-stage, parallel) ----------------

__global__ __launch_bounds__(128) void mean1_kernel(const float* __restrict__ h,
                                                    float* __restrict__ partials, int n) {
    int c = threadIdx.x;
    float acc = 0.f;
    for (int r = blockIdx.x; r < n; r += gridDim.x)
        acc += h[(size_t)r * 128 + c];
    partials[blockIdx.x * 128 + c] = acc;
}

__global__ __launch_bounds__(1024) void mean2_kernel(const float* __restrict__ partials,
                                                     float* __restrict__ out, int nb, int n) {
    __shared__ float smem[8][128];
    int c = threadIdx.x & 127;
    int g = threadIdx.x >> 7;  // 0..7
    float acc = 0.f;
    for (int r = g; r < nb; r += 8)
        acc += partials[r * 128 + c];
    smem[g][c] = acc;
    __syncthreads();
    if (threadIdx.x < 128) {
        float s = 0.f;
        #pragma unroll
        for (int k = 0; k < 8; ++k) s += smem[k][c];
        out[c] = s * (1.f / n);
    }
}

extern "C" void kernel_launch(void* const* d_in, const int* in_sizes, int n_in,
                              void* d_out, int out_size, void* d_ws, size_t ws_size,
                              hipStream_t stream) {
    const float* node_feats = (const float*)d_in[0];
    const int* src = (const int*)d_in[1];
    const int* dst = (const int*)d_in[2];
    const float* W_in = (const float*)d_in[3];
    const float* b_in = (const float*)d_in[4];
    const float* W_src = (const float*)d_in[5];
    const float* b_src = (const float*)d_in[6];
    const float* W_dst = (const float*)d_in[7];
    const float* b_dst = (const float*)d_in[8];
    const float* attn = (const float*)d_in[9];
    const float* ln_g = (const float*)d_in[10];
    const float* ln_b = (const float*)d_in[11];
    float* out = (float*)d_out;

    const int N = NN;
    const int E = in_sizes[1];

    // workspace layout (h bf16-only; no xB)
    unsigned short* fsB = (unsigned short*)d_ws;      // N*128 bf16
    unsigned short* fdB = fsB + (size_t)N * 128;      // N*128 bf16
    unsigned short* hB = fdB + (size_t)N * 128;       // N*128 bf16
    unsigned short* WtL = hB + (size_t)N * 128;       // 3*256*128 bf16
    unsigned short* WtIn = WtL + 3 * 32768;           // 128*64 bf16
    int* counts = (int*)(WtIn + 8192);                // N  (memset with total)
    int* total = counts + N;                          // 1
    int* row_beg = total + 1;                         // N
    int* rankb = row_beg + N;                         // E
    int* colb = rankb + E;                            // E+N
    float* partials = (float*)(colb + (E + N));       // 256*128

    // --- CSR build: one atomic pass (hist+rank), alloc, atomic-free scatter ---
    hipMemsetAsync(counts, 0, (size_t)(N + 1) * sizeof(int), stream);
    hist_rank_kernel<<<(E + 255) / 256, 256, 0, stream>>>(dst, counts, rankb, E);
    alloc_kernel<<<(N + 255) / 256, 256, 0, stream>>>(counts, row_beg, total, N);
    scatter_kernel<<<(E + N + 255) / 256, 256, 0, stream>>>(src, dst, rankb, row_beg,
                                                            counts, colb, E, N);

    // --- bf16 weight conversion ---
    convert_w_kernel<<<416, 256, 0, stream>>>(W_src, W_dst, W_in, WtL, WtIn);

    // --- input projection (MFMA, inline f32->bf16 A-frags) ---
    in_proj_mfma<<<512, 256, 0, stream>>>(node_feats, WtIn, b_in, hB);

    // --- 3 GATv2 layers ---
    const int NT = (N + 63) / 64;   // 782 dual tiles
    for (int l = 0; l < 3; ++l) {
        int last = (l == 2);
        dual_gemm_mfma<<<NT, 256, 0, stream>>>(hB, WtL + (size_t)l * 32768,
                                               b_src + l * 128, b_dst + l * 128,
                                               fsB, fdB);
        agg_ln_kernel<<<(N + 7) / 8, 256, 0, stream>>>(hB, fsB, fdB, row_beg, counts, colb,
                                                       attn + l * 128, ln_g + l * 128,
                                                       ln_b + l * 128,
                                                       last ? nullptr : hB,
                                                       last ? (out + 128) : nullptr, N);
    }

    // --- graph mean into out[0:128] ---
    mean1_kernel<<<256, 128, 0, stream>>>(out + 128, partials, N);
    mean2_kernel<<<1, 1024, 0, stream>>>(partials, out, 256, N);
}

// Round 17
// 420.083 us; speedup vs baseline: 1.0197x; 1.0138x over previous
//
#include <hip/hip_runtime.h>
#include <hip/hip_bf16.h>

#define NN 50000
#define CSTRIDE 16   // one counter per 64B line: 256 atomics/line -> 16/line

typedef short short8 __attribute__((ext_vector_type(8)));
typedef float f32x4 __attribute__((ext_vector_type(4)));

#define GLOBAL_AS __attribute__((address_space(1)))
#define LDS_AS __attribute__((address_space(3)))

__device__ __forceinline__ unsigned short f2bf(float f) {
    unsigned int b = __float_as_uint(f);
    unsigned int r = (b + 0x7FFFu + ((b >> 16) & 1u)) >> 16;   // RNE
    return (unsigned short)r;
}
__device__ __forceinline__ float bf2f(unsigned short u) {
    return __uint_as_float((unsigned int)u << 16);
}

// ---------------- CSR build ----------------
// countsS[] is line-strided (CSTRIDE ints apart): r7/r9 data shows device-scope
// atomic throughput scales ~sqrt(lines); 200KB-packed counts had 256 RMWs/line.

__global__ void hist_rank_kernel(const int* __restrict__ dst, int* countsS,
                                 int* __restrict__ rank, int E) {
    int i = blockIdx.x * blockDim.x + threadIdx.x;
    if (i < E) rank[i] = atomicAdd(&countsS[(size_t)dst[i] * CSTRIDE], 1);
}

__global__ __launch_bounds__(256) void alloc_kernel(const int* __restrict__ countsS,
                                                    int* __restrict__ row_beg,
                                                    int* total, int n) {
    int i = blockIdx.x * blockDim.x + threadIdx.x;
    int lane = threadIdx.x & 63;
    int len = (i < n) ? (countsS[(size_t)i * CSTRIDE] + 1) : 0;
    int p = len;
    #pragma unroll
    for (int off = 1; off < 64; off <<= 1) {
        int t = __shfl_up(p, off);
        if (lane >= off) p += t;
    }
    int tot = __shfl(p, 63);
    int base = 0;
    if (lane == 63) base = atomicAdd(total, tot);
    base = __shfl(base, 63);
    if (i < n) row_beg[i] = base + p - len;
}

__global__ void scatter_kernel(const int* __restrict__ src, const int* __restrict__ dst,
                               const int* __restrict__ rank, const int* __restrict__ row_beg,
                               const int* __restrict__ countsS,
                               int* __restrict__ col, int E, int n) {
    int i = blockIdx.x * blockDim.x + threadIdx.x;
    if (i >= E + n) return;
    if (i < E) {
        col[row_beg[dst[i]] + rank[i]] = src[i];
    } else {
        int v = i - E;
        col[row_beg[v] + countsS[(size_t)v * CSTRIDE]] = v;
    }
}

// ---------------- bf16 weight conversion ----------------
__global__ __launch_bounds__(256) void convert_w_kernel(const float* __restrict__ Ws,
                                                        const float* __restrict__ Wd,
                                                        const float* __restrict__ Win,
                                                        unsigned short* __restrict__ WtL,
                                                        unsigned short* __restrict__ WtIn) {
    int blk = blockIdx.x;
    if (blk < 384) {
        int e = blk * 256 + threadIdx.x;  // 0..98303
        int l = e >> 15;
        int r = e & 32767;
        int colc = r >> 7;
        int k = r & 127;
        float v = (colc < 128) ? Ws[l * 16384 + k * 128 + colc]
                               : Wd[l * 16384 + k * 128 + (colc - 128)];
        WtL[l * 32768 + colc * 128 + k] = f2bf(v);
    } else {
        int e = (blk - 384) * 256 + threadIdx.x;  // 0..8191
        int colc = e >> 6;
        int k = e & 63;
        WtIn[colc * 64 + k] = f2bf(Win[k * 128 + colc]);
    }
}

// ---------------- MFMA GEMMs ----------------
// in_proj: x_f32[N,64] @ W_in[64,128] + b -> hB (bf16), x converted inline.
__global__ __launch_bounds__(256, 4) void in_proj_mfma(const float* __restrict__ x,
                                                       const unsigned short* __restrict__ Wt,
                                                       const float* __restrict__ b,
                                                       unsigned short* __restrict__ hB) {
    int tid = threadIdx.x;
    int w = tid >> 6, l = tid & 63;
    int m = l & 15, q = l >> 4;
    short8 B[2][2];
    #pragma unroll
    for (int ct = 0; ct < 2; ++ct) {
        int col = w * 32 + ct * 16 + m;
        const unsigned short* wp = Wt + col * 64 + q * 8;
        #pragma unroll
        for (int kt = 0; kt < 2; ++kt) B[ct][kt] = *(const short8*)(wp + kt * 32);
    }
    float bias[2];
    #pragma unroll
    for (int ct = 0; ct < 2; ++ct) bias[ct] = b[w * 32 + ct * 16 + m];
    for (int rg = blockIdx.x; rg < NN / 16; rg += gridDim.x) {
        int row0 = rg * 16;
        const float* ap = x + (size_t)(row0 + m) * 64 + q * 8;
        short8 A[2];
        #pragma unroll
        for (int kt = 0; kt < 2; ++kt) {
            float4 f0 = *(const float4*)(ap + kt * 32);
            float4 f1 = *(const float4*)(ap + kt * 32 + 4);
            short8 a;
            a[0] = (short)f2bf(f0.x); a[1] = (short)f2bf(f0.y);
            a[2] = (short)f2bf(f0.z); a[3] = (short)f2bf(f0.w);
            a[4] = (short)f2bf(f1.x); a[5] = (short)f2bf(f1.y);
            a[6] = (short)f2bf(f1.z); a[7] = (short)f2bf(f1.w);
            A[kt] = a;
        }
        f32x4 acc[2];
        #pragma unroll
        for (int ct = 0; ct < 2; ++ct) acc[ct] = (f32x4){0.f, 0.f, 0.f, 0.f};
        #pragma unroll
        for (int kt = 0; kt < 2; ++kt)
            #pragma unroll
            for (int ct = 0; ct < 2; ++ct)
                acc[ct] = __builtin_amdgcn_mfma_f32_16x16x32_bf16(A[kt], B[ct][kt], acc[ct], 0, 0, 0);
        #pragma unroll
        for (int ct = 0; ct < 2; ++ct) {
            int col = w * 32 + ct * 16 + m;
            #pragma unroll
            for (int i = 0; i < 4; ++i) {
                int row = row0 + q * 4 + i;
                hB[(size_t)row * 128 + col] = f2bf(acc[ct][i] + bias[ct]);
            }
        }
    }
}

// dual: LDS-staged A-tile, grid-stride.
__global__ __launch_bounds__(256, 4) void dual_gemm_mfma(const unsigned short* __restrict__ hB,
                                                         const unsigned short* __restrict__ Wt,
                                                         const float* __restrict__ bs,
                                                         const float* __restrict__ bd,
                                                         unsigned short* __restrict__ fsB,
                                                         unsigned short* __restrict__ fdB) {
    __shared__ unsigned short Atile[64 * 128];   // 16 KB
    int tid = threadIdx.x;
    int w = tid >> 6, l = tid & 63;
    int m = l & 15, q = l >> 4;
    short8 B[4][4];
    #pragma unroll
    for (int ct = 0; ct < 4; ++ct) {
        int col = w * 64 + ct * 16 + m;
        const unsigned short* wp = Wt + col * 128 + q * 8;
        #pragma unroll
        for (int kt = 0; kt < 4; ++kt) B[ct][kt] = *(const short8*)(wp + kt * 32);
    }
    const float* bptr = (w < 2) ? bs : bd;
    unsigned short* OUT = (w < 2) ? fsB : fdB;
    int ocb = (w * 64) & 127;
    float bias[4];
    #pragma unroll
    for (int ct = 0; ct < 4; ++ct) bias[ct] = bptr[ocb + ct * 16 + m];

    const int NT = (NN + 63) / 64;   // 782 tiles
    for (int t = blockIdx.x; t < NT; t += gridDim.x) {
        int row0 = t * 64;
        const char* gsrc = (const char*)(hB + (size_t)row0 * 128);
        #pragma unroll
        for (int c = 0; c < 4; ++c) {
            int off = c * 4096 + tid * 16;
            __builtin_amdgcn_global_load_lds((const GLOBAL_AS void*)(gsrc + off),
                                             (LDS_AS void*)((char*)Atile + off), 16, 0, 0);
        }
        __syncthreads();
        #pragma unroll
        for (int rg = 0; rg < 4; ++rg) {
            const unsigned short* ap = Atile + (rg * 16 + m) * 128 + q * 8;
            short8 A[4];
            #pragma unroll
            for (int kt = 0; kt < 4; ++kt) A[kt] = *(const short8*)(ap + kt * 32);
            f32x4 acc[4];
            #pragma unroll
            for (int ct = 0; ct < 4; ++ct) acc[ct] = (f32x4){0.f, 0.f, 0.f, 0.f};
            #pragma unroll
            for (int kt = 0; kt < 4; ++kt)
                #pragma unroll
                for (int ct = 0; ct < 4; ++ct)
                    acc[ct] = __builtin_amdgcn_mfma_f32_16x16x32_bf16(A[kt], B[ct][kt], acc[ct], 0, 0, 0);
            #pragma unroll
            for (int ct = 0; ct < 4; ++ct) {
                int col = ocb + ct * 16 + m;
                #pragma unroll
                for (int i = 0; i < 4; ++i) {
                    int row = row0 + rg * 16 + q * 4 + i;
                    if (row < NN) OUT[(size_t)row * 128 + col] = f2bf(acc[ct][i] + bias[ct]);
                }
            }
        }
        __syncthreads();
    }
}

// ---------------- fused gather attention + residual + LN + relu ----------------
// 2 dst nodes/wave, 4 feats/lane, everything bf16 in. No-max softmax, x4 ILP
// (r8-proven body, measured floor ~55 us). h bf16-only; layer 2 -> f32 hf_out.
__global__ __launch_bounds__(256) void agg_ln_kernel(const unsigned short* __restrict__ h_in,
                                                     const unsigned short* __restrict__ fsB,
                                                     const unsigned short* __restrict__ fdB,
                                                     const int* __restrict__ row_beg,
                                                     const int* __restrict__ countsS,
                                                     const int* __restrict__ col,
                                                     const float* __restrict__ attn,
                                                     const float* __restrict__ ln_g,
                                                     const float* __restrict__ ln_b,
                                                     unsigned short* __restrict__ hb_out,
                                                     float* __restrict__ hf_out, int n) {
    int gwave = (blockIdx.x * blockDim.x + threadIdx.x) >> 6;
    int lane = threadIdx.x & 63;
    int half = lane >> 5;
    int sub = lane & 31;
    int node = gwave * 2 + half;
    if (node >= n) return;
    int f0 = 4 * sub;
    ushort4 ud = *(const ushort4*)(fdB + (size_t)node * 128 + f0);
    float4 fd4;
    fd4.x = bf2f(ud.x); fd4.y = bf2f(ud.y); fd4.z = bf2f(ud.z); fd4.w = bf2f(ud.w);
    ushort4 uh = *(const ushort4*)(h_in + (size_t)node * 128 + f0);
    float4 h4;
    h4.x = bf2f(uh.x); h4.y = bf2f(uh.y); h4.z = bf2f(uh.z); h4.w = bf2f(uh.w);
    const float4 a4 = *(const float4*)(attn + f0);
    int beg = row_beg[node], end = beg + countsS[(size_t)node * CSTRIDE] + 1;

    float z[4];
    float4 acc[4];
    #pragma unroll
    for (int k = 0; k < 4; ++k) {
        z[k] = 0.f;
        acc[k].x = 0.f; acc[k].y = 0.f; acc[k].z = 0.f; acc[k].w = 0.f;
    }

    int j = beg;
    for (; j + 3 < end; j += 4) {
        int s0 = col[j], s1 = col[j + 1], s2 = col[j + 2], s3 = col[j + 3];
        ushort4 u0 = *(const ushort4*)(fsB + (size_t)s0 * 128 + f0);
        ushort4 u1 = *(const ushort4*)(fsB + (size_t)s1 * 128 + f0);
        ushort4 u2 = *(const ushort4*)(fsB + (size_t)s2 * 128 + f0);
        ushort4 u3 = *(const ushort4*)(fsB + (size_t)s3 * 128 + f0);
        float4 v0, v1, v2, v3;
        v0.x = bf2f(u0.x); v0.y = bf2f(u0.y); v0.z = bf2f(u0.z); v0.w = bf2f(u0.w);
        v1.x = bf2f(u1.x); v1.y = bf2f(u1.y); v1.z = bf2f(u1.z); v1.w = bf2f(u1.w);
        v2.x = bf2f(u2.x); v2.y = bf2f(u2.y); v2.z = bf2f(u2.z); v2.w = bf2f(u2.w);
        v3.x = bf2f(u3.x); v3.y = bf2f(u3.y); v3.z = bf2f(u3.z); v3.w = bf2f(u3.w);
        float p0, p1, p2, p3;
        {
            float e0 = v0.x + fd4.x; e0 = fmaxf(e0, 0.2f * e0);
            float e1 = v0.y + fd4.y; e1 = fmaxf(e1, 0.2f * e1);
            float e2 = v0.z + fd4.z; e2 = fmaxf(e2, 0.2f * e2);
            float e3 = v0.w + fd4.w; e3 = fmaxf(e3, 0.2f * e3);
            p0 = e0 * a4.x + e1 * a4.y + e2 * a4.z + e3 * a4.w;
        }
        {
            float e0 = v1.x + fd4.x; e0 = fmaxf(e0, 0.2f * e0);
            float e1 = v1.y + fd4.y; e1 = fmaxf(e1, 0.2f * e1);
            float e2 = v1.z + fd4.z; e2 = fmaxf(e2, 0.2f * e2);
            float e3 = v1.w + fd4.w; e3 = fmaxf(e3, 0.2f * e3);
            p1 = e0 * a4.x + e1 * a4.y + e2 * a4.z + e3 * a4.w;
        }
        {
            float e0 = v2.x + fd4.x; e0 = fmaxf(e0, 0.2f * e0);
            float e1 = v2.y + fd4.y; e1 = fmaxf(e1, 0.2f * e1);
            float e2 = v2.z + fd4.z; e2 = fmaxf(e2, 0.2f * e2);
            float e3 = v2.w + fd4.w; e3 = fmaxf(e3, 0.2f * e3);
            p2 = e0 * a4.x + e1 * a4.y + e2 * a4.z + e3 * a4.w;
        }
        {
            float e0 = v3.x + fd4.x; e0 = fmaxf(e0, 0.2f * e0);
            float e1 = v3.y + fd4.y; e1 = fmaxf(e1, 0.2f * e1);
            float e2 = v3.z + fd4.z; e2 = fmaxf(e2, 0.2f * e2);
            float e3 = v3.w + fd4.w; e3 = fmaxf(e3, 0.2f * e3);
            p3 = e0 * a4.x + e1 * a4.y + e2 * a4.z + e3 * a4.w;
        }
        #pragma unroll
        for (int off = 1; off <= 4; off <<= 1) {
            p0 += __shfl_xor(p0, off);
            p1 += __shfl_xor(p1, off);
            p2 += __shfl_xor(p2, off);
            p3 += __shfl_xor(p3, off);
        }
        float w0 = __expf(p0), w1 = __expf(p1), w2 = __expf(p2), w3 = __expf(p3);
        z[0] += w0; z[1] += w1; z[2] += w2; z[3] += w3;
        acc[0].x += w0 * v0.x; acc[0].y += w0 * v0.y; acc[0].z += w0 * v0.z; acc[0].w += w0 * v0.w;
        acc[1].x += w1 * v1.x; acc[1].y += w1 * v1.y; acc[1].z += w1 * v1.z; acc[1].w += w1 * v1.w;
        acc[2].x += w2 * v2.x; acc[2].y += w2 * v2.y; acc[2].z += w2 * v2.z; acc[2].w += w2 * v2.w;
        acc[3].x += w3 * v3.x; acc[3].y += w3 * v3.y; acc[3].z += w3 * v3.z; acc[3].w += w3 * v3.w;
    }
    for (; j < end; ++j) {
        int s = col[j];
        ushort4 u = *(const ushort4*)(fsB + (size_t)s * 128 + f0);
        float4 v;
        v.x = bf2f(u.x); v.y = bf2f(u.y); v.z = bf2f(u.z); v.w = bf2f(u.w);
        float e0 = v.x + fd4.x; e0 = fmaxf(e0, 0.2f * e0);
        float e1 = v.y + fd4.y; e1 = fmaxf(e1, 0.2f * e1);
        float e2 = v.z + fd4.z; e2 = fmaxf(e2, 0.2f * e2);
        float e3 = v.w + fd4.w; e3 = fmaxf(e3, 0.2f * e3);
        float p = e0 * a4.x + e1 * a4.y + e2 * a4.z + e3 * a4.w;
        p += __shfl_xor(p, 1);
        p += __shfl_xor(p, 2);
        p += __shfl_xor(p, 4);
        float w = __expf(p);
        z[0] += w;
        acc[0].x += w * v.x; acc[0].y += w * v.y; acc[0].z += w * v.z; acc[0].w += w * v.w;
    }
    float zT = (z[0] + z[1]) + (z[2] + z[3]);
    float axT = (acc[0].x + acc[1].x) + (acc[2].x + acc[3].x);
    float ayT = (acc[0].y + acc[1].y) + (acc[2].y + acc[3].y);
    float azT = (acc[0].z + acc[1].z) + (acc[2].z + acc[3].z);
    float awT = (acc[0].w + acc[1].w) + (acc[2].w + acc[3].w);
    float inv = 1.0f / zT;
    float x0 = 2.f * h4.x + axT * inv;  // h + (aggr + h)
    float x1 = 2.f * h4.y + ayT * inv;
    float x2 = 2.f * h4.z + azT * inv;
    float x3 = 2.f * h4.w + awT * inv;
    float s = (x0 + x1) + (x2 + x3);
    #pragma unroll
    for (int off = 1; off <= 16; off <<= 1) s += __shfl_xor(s, off);
    float mean = s * (1.f / 128.f);
    float d0 = x0 - mean, d1 = x1 - mean, d2 = x2 - mean, d3 = x3 - mean;
    float v = (d0 * d0 + d1 * d1) + (d2 * d2 + d3 * d3);
    #pragma unroll
    for (int off = 1; off <= 16; off <<= 1) v += __shfl_xor(v, off);
    float rstd = rsqrtf(v * (1.f / 128.f) + 1e-5f);
    float4 g4 = *(const float4*)(ln_g + f0);
    float4 bb4 = *(const float4*)(ln_b + f0);
    float4 o;
    o.x = fmaxf(d0 * rstd * g4.x + bb4.x, 0.f);
    o.y = fmaxf(d1 * rstd * g4.y + bb4.y, 0.f);
    o.z = fmaxf(d2 * rstd * g4.z + bb4.z, 0.f);
    o.w = fmaxf(d3 * rstd * g4.w + bb4.w, 0.f);
    if (hf_out) {
        *(float4*)(hf_out + (size_t)node * 128 + f0) = o;
    } else {
        ushort4 ob;
        ob.x = f2bf(o.x); ob.y = f2bf(o.y); ob.z = f2bf(o.z); ob.w = f2bf(o.w);
        *(ushort4*)(hb_out + (size_t)node * 128 + f0) = ob;
    }
}

// ---------------- graph mean (two-stage, parallel) ----------------

__global__ __launch_bounds__(128) void mean1_kernel(const float* __restrict__ h,
                                                    float* __restrict__ partials, int n) {
    int c = threadIdx.x;
    float acc = 0.f;
    for (int r = blockIdx.x; r < n; r += gridDim.x)
        acc += h[(size_t)r * 128 + c];
    partials[blockIdx.x * 128 + c] = acc;
}

__global__ __launch_bounds__(1024) void mean2_kernel(const float* __restrict__ partials,
                                                     float* __restrict__ out, int nb, int n) {
    __shared__ float smem[8][128];
    int c = threadIdx.x & 127;
    int g = threadIdx.x >> 7;  // 0..7
    float acc = 0.f;
    for (int r = g; r < nb; r += 8)
        acc += partials[r * 128 + c];
    smem[g][c] = acc;
    __syncthreads();
    if (threadIdx.x < 128) {
        float s = 0.f;
        #pragma unroll
        for (int k = 0; k < 8; ++k) s += smem[k][c];
        out[c] = s * (1.f / n);
    }
}

extern "C" void kernel_launch(void* const* d_in, const int* in_sizes, int n_in,
                              void* d_out, int out_size, void* d_ws, size_t ws_size,
                              hipStream_t stream) {
    const float* node_feats = (const float*)d_in[0];
    const int* src = (const int*)d_in[1];
    const int* dst = (const int*)d_in[2];
    const float* W_in = (const float*)d_in[3];
    const float* b_in = (const float*)d_in[4];
    const float* W_src = (const float*)d_in[5];
    const float* b_src = (const float*)d_in[6];
    const float* W_dst = (const float*)d_in[7];
    const float* b_dst = (const float*)d_in[8];
    const float* attn = (const float*)d_in[9];
    const float* ln_g = (const float*)d_in[10];
    const float* ln_b = (const float*)d_in[11];
    float* out = (float*)d_out;

    const int N = NN;
    const int E = in_sizes[1];

    // workspace layout (h bf16-only; countsS line-strided)
    unsigned short* fsB = (unsigned short*)d_ws;      // N*128 bf16
    unsigned short* fdB = fsB + (size_t)N * 128;      // N*128 bf16
    unsigned short* hB = fdB + (size_t)N * 128;       // N*128 bf16
    unsigned short* WtL = hB + (size_t)N * 128;       // 3*256*128 bf16
    unsigned short* WtIn = WtL + 3 * 32768;           // 128*64 bf16
    int* countsS = (int*)(WtIn + 8192);               // N*CSTRIDE (memset w/ total)
    int* total = countsS + (size_t)N * CSTRIDE;       // 1
    int* row_beg = total + 1;                         // N
    int* rankb = row_beg + N;                         // E
    int* colb = rankb + E;                            // E+N
    float* partials = (float*)(colb + (E + N));       // 256*128

    // --- CSR build: one atomic pass (hist+rank), alloc, atomic-free scatter ---
    hipMemsetAsync(countsS, 0, ((size_t)N * CSTRIDE + 1) * sizeof(int), stream);
    hist_rank_kernel<<<(E + 255) / 256, 256, 0, stream>>>(dst, countsS, rankb, E);
    alloc_kernel<<<(N + 255) / 256, 256, 0, stream>>>(countsS, row_beg, total, N);
    scatter_kernel<<<(E + N + 255) / 256, 256, 0, stream>>>(src, dst, rankb, row_beg,
                                                            countsS, colb, E, N);

    // --- bf16 weight conversion ---
    convert_w_kernel<<<416, 256, 0, stream>>>(W_src, W_dst, W_in, WtL, WtIn);

    // --- input projection (MFMA, inline f32->bf16 A-frags) ---
    in_proj_mfma<<<512, 256, 0, stream>>>(node_feats, WtIn, b_in, hB);

    // --- 3 GATv2 layers ---
    const int NT = (N + 63) / 64;   // 782 dual tiles
    for (int l = 0; l < 3; ++l) {
        int last = (l == 2);
        dual_gemm_mfma<<<NT, 256, 0, stream>>>(hB, WtL + (size_t)l * 32768,
                                               b_src + l * 128, b_dst + l * 128,
                                               fsB, fdB);
        agg_ln_kernel<<<(N + 7) / 8, 256, 0, stream>>>(hB, fsB, fdB, row_beg, countsS, colb,
                                                       attn + l * 128, ln_g + l * 128,
                                                       ln_b + l * 128,
                                                       last ? nullptr : hB,
                                                       last ? (out + 128) : nullptr, N);
    }

    // --- graph mean into out[0:128] ---
    mean1_kernel<<<256, 128, 0, stream>>>(out + 128, partials, N);
    mean2_kernel<<<1, 1024, 0, stream>>>(partials, out, 256, N);
}